// Round 3
// baseline (660.987 us; speedup 1.0000x reference)
//
#include <hip/hip_runtime.h>
#include <cstddef>
#include <cstdint>

// ---------------------------------------------------------------------------
// Problem constants (ImplicitHead2D_Seq_MS_Deform)
// ---------------------------------------------------------------------------
#define B_    8
#define NQ_   900
#define C_    256
#define M_    8
#define P_    4
#define L_    4
#define D_    32
#define S_    19560
#define NC_   10
#define FFN_  1024
#define RQ_   (B_ * NQ_)   // 7200 query rows
#define RV_   (B_ * S_)    // 156480 value rows

typedef __attribute__((ext_vector_type(8))) short bf8_t;   // 8 x bf16
typedef __attribute__((ext_vector_type(4))) float f4_t;    // 4 x f32
typedef unsigned short ushort_t;

__device__ __forceinline__ unsigned short f2bf(float x) {
    union { float f; unsigned u; } v; v.f = x;
    unsigned r = v.u + 0x7FFF + ((v.u >> 16) & 1);   // round-nearest-even
    return (unsigned short)(r >> 16);
}
__device__ __forceinline__ float bfu2f(unsigned short u) {
    union { unsigned u; float f; } v; v.u = ((unsigned)u) << 16; return v.f;
}

// ---------------------------------------------------------------------------
// Weight prep: fp32 W[K][N] -> bf16 W^T[N][K].  64x64 tiles via LDS.
// ---------------------------------------------------------------------------
__global__ __launch_bounds__(256) void prep_weights(
    const float* __restrict__ w_value, const float* __restrict__ w_off,
    const float* __restrict__ w_attn,  const float* __restrict__ w_out,
    const float* __restrict__ w_ffn1,  const float* __restrict__ w_ffn2,
    short* __restrict__ WvT, short* __restrict__ WoaT, short* __restrict__ WoutT,
    short* __restrict__ Wf1T, short* __restrict__ Wf2T)
{
    const int mat = blockIdx.z;
    int K, N; const float* src; short* dst;
    switch (mat) {
        case 0: K = 256;  N = 256;  src = w_value; dst = WvT;  break;
        case 1: K = 256;  N = 384;  src = nullptr; dst = WoaT; break;
        case 2: K = 256;  N = 256;  src = w_out;   dst = WoutT; break;
        case 3: K = 256;  N = 1024; src = w_ffn1;  dst = Wf1T; break;
        default:K = 1024; N = 256;  src = w_ffn2;  dst = Wf2T; break;
    }
    const int ntn = N >> 6;
    const int kt = blockIdx.x / ntn, nt = blockIdx.x % ntn;
    if (kt >= (K >> 6)) return;

    __shared__ float t[64][65];
    const int tx = threadIdx.x & 63;
    const int ty = threadIdx.x >> 6;
#pragma unroll
    for (int i = 0; i < 64; i += 4) {
        const int k = kt * 64 + i + ty;
        const int n = nt * 64 + tx;
        float v;
        if (mat == 1) v = (n < 256) ? w_off[(size_t)k * 256 + n]
                                    : w_attn[(size_t)k * 128 + (n - 256)];
        else          v = src[(size_t)k * N + n];
        t[i + ty][tx] = v;
    }
    __syncthreads();
#pragma unroll
    for (int i = 0; i < 64; i += 4) {
        const int n = nt * 64 + i + ty;
        const int k = kt * 64 + tx;
        dst[(size_t)n * K + k] = (short)f2bf(t[tx][i + ty]);
    }
}

__global__ __launch_bounds__(384) void prep_bias(
    const float* __restrict__ b_off, const float* __restrict__ b_attn,
    float* __restrict__ bias_cat)
{
    const int t = threadIdx.x;
    bias_cat[t] = (t < 256) ? b_off[t] : b_attn[t - 256];
}

// ---------------------------------------------------------------------------
// bf16 MFMA GEMM, register-double-buffered K pipeline.
//  out[R,N] = A[R,K](fp32) @ WT(bf16 [N][K]) + bias
//  MODE 0: plain fp32   MODE 1: bf16 value-permute -> v[B,M,S,D] (BM=128 only)
//  MODE 2: relu fp32    MODE 3: residual fp32 (+res[r*N+n])
//  BM in {128, 64}; BN=128; BK=64; 4 waves (2x2), wave tile (BM/2)x64.
//  LDS XOR-swizzled on 16B units (u ^ (row&7)) for conflict-free ds_read_b128.
// ---------------------------------------------------------------------------
template <int MODE, int BM>
__global__ __launch_bounds__(256) void gemm_mfma(
    const float* __restrict__ A, const short* __restrict__ WT,
    const float* __restrict__ bias, const float* __restrict__ res,
    float* __restrict__ out, int R, int N, int K)
{
    constexpr int NI  = BM / 32;          // acc rows per wave (4 or 2)
    constexpr int AIT = BM * 8 / 256;     // A staging iters (4 or 2)
    constexpr int ASB = BM * 128;         // As bytes
    constexpr int SMEM_BYTES = (MODE == 1) ? (128 * 136 * 2) : (ASB + 16384);

    __shared__ __align__(16) char smem[SMEM_BYTES];
    short* As = (short*)smem;             // [BM][64] swizzled
    short* Bs = (short*)(smem + ASB);     // [128][64] swizzled

    const int tid  = threadIdx.x;
    const int lane = tid & 63;
    const int wave = tid >> 6;
    const int wr   = wave >> 1;
    const int wc   = wave & 1;
    const int g    = lane >> 4;           // 0..3
    const int fr   = lane & 15;

    const int row0 = blockIdx.x * BM;
    const int col0 = blockIdx.y * 128;

    const int r_base = tid >> 3;          // 0..31
    const int ku     = tid & 7;           // 0..7 (8-elem k-chunk)

    float4 rA[AIT][2];
#pragma unroll
    for (int it = 0; it < AIT; ++it) {
        rA[it][0] = make_float4(0.f, 0.f, 0.f, 0.f);
        rA[it][1] = make_float4(0.f, 0.f, 0.f, 0.f);
    }
    int4 rB[4];

    f4_t acc[NI][4] = {};

    auto LOAD = [&](int k0) {
#pragma unroll
        for (int it = 0; it < AIT; ++it) {
            const int grow = row0 + it * 32 + r_base;
            if (grow < R) {
                rA[it][0] = *(const float4*)(A + (size_t)grow * K + k0 + ku * 8);
                rA[it][1] = *(const float4*)(A + (size_t)grow * K + k0 + ku * 8 + 4);
            }
        }
#pragma unroll
        for (int it = 0; it < 4; ++it) {
            const int n = it * 32 + r_base;
            rB[it] = *(const int4*)(WT + (size_t)(col0 + n) * K + k0 + ku * 8);
        }
    };
    auto WRITE = [&]() {
#pragma unroll
        for (int it = 0; it < AIT; ++it) {
            const int r = it * 32 + r_base;
            const float va[8] = {rA[it][0].x, rA[it][0].y, rA[it][0].z, rA[it][0].w,
                                 rA[it][1].x, rA[it][1].y, rA[it][1].z, rA[it][1].w};
            bf8_t pk;
#pragma unroll
            for (int j = 0; j < 8; ++j) pk[j] = (short)f2bf(va[j]);
            *(bf8_t*)&As[r * 64 + (ku ^ (r & 7)) * 8] = pk;
        }
#pragma unroll
        for (int it = 0; it < 4; ++it) {
            const int n = it * 32 + r_base;
            *(int4*)&Bs[n * 64 + (ku ^ (n & 7)) * 8] = rB[it];
        }
    };

    LOAD(0);
    for (int k0 = 0; k0 < K; k0 += 64) {
        WRITE();
        __syncthreads();
        if (k0 + 64 < K) LOAD(k0 + 64);   // in flight during MFMA phase
#pragma unroll
        for (int c = 0; c < 2; ++c) {
            bf8_t fa[NI], fb[4];
#pragma unroll
            for (int i = 0; i < NI; ++i) {
                const int ar = wr * (BM / 2) + i * 16 + fr;
                fa[i] = *(const bf8_t*)&As[ar * 64 + ((c * 4 + g) ^ (ar & 7)) * 8];
            }
#pragma unroll
            for (int j = 0; j < 4; ++j) {
                const int br = wc * 64 + j * 16 + fr;
                fb[j] = *(const bf8_t*)&Bs[br * 64 + ((c * 4 + g) ^ (br & 7)) * 8];
            }
#pragma unroll
            for (int i = 0; i < NI; ++i)
#pragma unroll
                for (int j = 0; j < 4; ++j)
                    acc[i][j] = __builtin_amdgcn_mfma_f32_16x16x32_bf16(
                        fa[i], fb[j], acc[i][j], 0, 0, 0);
        }
        __syncthreads();
    }

    // ---- epilogue ----  D layout: col = lane&15 -> fr, row = g*4 + reg
    if (MODE == 1) {
        // bf16 value-permute epilogue via LDS repack -> coalesced 16B stores
        ushort_t* eps = (ushort_t*)smem;   // [128][136]
        ushort_t* outv = (ushort_t*)out;
#pragma unroll
        for (int j = 0; j < 4; ++j) {
            const int col_l = wc * 64 + j * 16 + fr;
            const float bcol = bias[col0 + col_l];
#pragma unroll
            for (int i = 0; i < NI; ++i)
#pragma unroll
                for (int r = 0; r < 4; ++r) {
                    const int row_l = wr * 64 + i * 16 + g * 4 + r;
                    eps[row_l * 136 + col_l] = f2bf(acc[i][j][r] + bcol);
                }
        }
        __syncthreads();
#pragma unroll
        for (int u = 0; u < 8; ++u) {
            const int unit = u * 256 + tid;
            const int sl = unit >> 4;         // 0..127 local row
            const int cc = unit & 15;         // 16B chunk
            const int grow = row0 + sl;
            if (grow < R) {
                const int b = grow / S_;
                const int s = grow - b * S_;
                const int col = col0 + cc * 8;
                const int m = col >> 5;
                const int d = col & 31;
                const int4 w = *(const int4*)&eps[sl * 136 + cc * 8];
                *(int4*)&outv[(((size_t)(b * M_ + m)) * S_ + s) * D_ + d] = w;
            }
        }
    } else {
#pragma unroll
        for (int j = 0; j < 4; ++j) {
            const int col = col0 + wc * 64 + j * 16 + fr;
            const float bcol = bias[col];
#pragma unroll
            for (int i = 0; i < NI; ++i) {
#pragma unroll
                for (int r = 0; r < 4; ++r) {
                    const int row = row0 + wr * (BM / 2) + i * 16 + g * 4 + r;
                    if (row >= R) continue;
                    float vv = acc[i][j][r] + bcol;
                    if (MODE == 2) {
                        out[(size_t)row * N + col] = fmaxf(vv, 0.f);
                    } else if (MODE == 3) {
                        out[(size_t)row * N + col] = vv + res[(size_t)row * N + col];
                    } else {
                        out[(size_t)row * N + col] = vv;
                    }
                }
            }
        }
    }
}

// ---------------------------------------------------------------------------
// Softmax over L*P=16 per head + bake sampling locations to pixel coords.
// oa row: [0..255] off (m*32+l*8+p*2+c), [256..383] attn logits (m*16+l*4+p).
// ---------------------------------------------------------------------------
__global__ __launch_bounds__(128) void softmax_loc_kernel(
    const float* __restrict__ oa, const float* __restrict__ ref,
    float* __restrict__ loc, float* __restrict__ attn)
{
    const int row = blockIdx.x;
    const int t   = threadIdx.x;       // 0..127 (m = t>>4)
    const float Wtab[L_] = {160.f, 80.f, 40.f, 20.f};
    const float Htab[L_] = {92.f, 46.f, 23.f, 12.f};

    float vlog = oa[(size_t)row * 384 + 256 + t];
    float mx = vlog;
#pragma unroll
    for (int o = 8; o >= 1; o >>= 1) mx = fmaxf(mx, __shfl_xor(mx, o, 64));
    const float e = __expf(vlog - mx);
    float sm = e;
#pragma unroll
    for (int o = 8; o >= 1; o >>= 1) sm += __shfl_xor(sm, o, 64);
    attn[(size_t)row * 128 + t] = e / sm;

    const int m = t >> 4, l = (t >> 2) & 3, p = t & 3;
    const float rx = ref[(size_t)row * 2 + 0];
    const float ry = ref[(size_t)row * 2 + 1];
    const int oi = m * 32 + l * 8 + p * 2;
    loc[(size_t)row * 256 + oi + 0] = rx * Wtab[l] + oa[(size_t)row * 384 + oi + 0] - 0.5f;
    loc[(size_t)row * 256 + oi + 1] = ry * Htab[l] + oa[(size_t)row * 384 + oi + 1] - 0.5f;
}

// ---------------------------------------------------------------------------
// Deformable sampling, bf16 v. grid 7200, block 256: thread = (m=t>>5, d=t&31).
// ---------------------------------------------------------------------------
__global__ __launch_bounds__(256) void sample_kernel(
    const ushort_t* __restrict__ v, const float* __restrict__ loc,
    const float* __restrict__ attn, float* __restrict__ outf)
{
    const int row = blockIdx.x;
    const int b   = row / NQ_;
    const int t   = threadIdx.x;
    const int m   = t >> 5;
    const int d   = t & 31;

    __shared__ float sloc[256];
    __shared__ float satt[128];
    sloc[t] = loc[(size_t)row * 256 + t];
    if (t < 128) satt[t] = attn[(size_t)row * 128 + t];
    __syncthreads();

    const int Wtab[L_] = {160, 80, 40, 20};
    const int Htab[L_] = {92, 46, 23, 12};
    const int Stab[L_] = {0, 14720, 18400, 19320};

    const ushort_t* vb = v + ((size_t)(b * M_ + m)) * S_ * D_ + d;
    float acc = 0.f;

#pragma unroll
    for (int l = 0; l < L_; ++l) {
        const int Wl = Wtab[l], Hl = Htab[l], st = Stab[l];
#pragma unroll
        for (int p = 0; p < P_; ++p) {
            const float x = sloc[m * 32 + l * 8 + p * 2 + 0];
            const float y = sloc[m * 32 + l * 8 + p * 2 + 1];
            const float a = satt[m * 16 + l * 4 + p];
            const float xf = floorf(x), yf = floorf(y);
            const int x0 = (int)xf, y0 = (int)yf;
            const float lx = x - xf, ly = y - yf;
            const float w00 = (1.f - lx) * (1.f - ly);
            const float w01 = lx * (1.f - ly);
            const float w10 = (1.f - lx) * ly;
            const float w11 = lx * ly;
            const bool xv0 = (x0 >= 0) && (x0 < Wl);
            const bool xv1 = (x0 + 1 >= 0) && (x0 + 1 < Wl);
            const bool yv0 = (y0 >= 0) && (y0 < Hl);
            const bool yv1 = (y0 + 1 >= 0) && (y0 + 1 < Hl);
            float s00 = 0.f, s01 = 0.f, s10 = 0.f, s11 = 0.f;
            if (xv0 && yv0) s00 = bfu2f(vb[(size_t)(st + y0 * Wl + x0) * D_]);
            if (xv1 && yv0) s01 = bfu2f(vb[(size_t)(st + y0 * Wl + x0 + 1) * D_]);
            if (xv0 && yv1) s10 = bfu2f(vb[(size_t)(st + (y0 + 1) * Wl + x0) * D_]);
            if (xv1 && yv1) s11 = bfu2f(vb[(size_t)(st + (y0 + 1) * Wl + x0 + 1) * D_]);
            acc += a * (w00 * s00 + w01 * s01 + w10 * s10 + w11 * s11);
        }
    }
    outf[(size_t)row * 256 + m * 32 + d] = acc;
}

// ---------------------------------------------------------------------------
// LayerNorm over C=256. grid = 7200, block = 64 (one wave), float4 per lane.
// ---------------------------------------------------------------------------
__global__ __launch_bounds__(64) void ln_kernel(
    const float* __restrict__ in, const float* __restrict__ w,
    const float* __restrict__ bp, float* __restrict__ out)
{
    const int row  = blockIdx.x;
    const int lane = threadIdx.x;
    const float4 x = ((const float4*)(in + (size_t)row * C_))[lane];
    float s = x.x + x.y + x.z + x.w;
#pragma unroll
    for (int o = 32; o >= 1; o >>= 1) s += __shfl_xor(s, o, 64);
    const float mean = s * (1.f / C_);
    const float d0 = x.x - mean, d1 = x.y - mean, d2 = x.z - mean, d3 = x.w - mean;
    float ss = d0 * d0 + d1 * d1 + d2 * d2 + d3 * d3;
#pragma unroll
    for (int o = 32; o >= 1; o >>= 1) ss += __shfl_xor(ss, o, 64);
    const float r = rsqrtf(ss * (1.f / C_) + 1e-6f);
    const float4 wv = ((const float4*)w)[lane];
    const float4 bv = ((const float4*)bp)[lane];
    float4 o4;
    o4.x = d0 * r * wv.x + bv.x;
    o4.y = d1 * r * wv.y + bv.y;
    o4.z = d2 * r * wv.z + bv.z;
    o4.w = d3 * r * wv.w + bv.w;
    ((float4*)(out + (size_t)row * C_))[lane] = o4;
}

// ---------------------------------------------------------------------------
// Classifier head: out[row,0..9] = x[row,:] @ w_cls + b_cls. grid=7200, block=64.
// ---------------------------------------------------------------------------
__global__ __launch_bounds__(64) void cls_kernel(
    const float* __restrict__ x, const float* __restrict__ w,
    const float* __restrict__ bias, float* __restrict__ out)
{
    const int row  = blockIdx.x;
    const int lane = threadIdx.x;
    float acc[NC_] = {};
#pragma unroll
    for (int j = 0; j < 4; ++j) {
        const int k = lane + j * 64;
        const float xk = x[(size_t)row * C_ + k];
        const float* wr = w + (size_t)k * NC_;
#pragma unroll
        for (int n = 0; n < NC_; ++n) acc[n] += xk * wr[n];
    }
#pragma unroll
    for (int n = 0; n < NC_; ++n) {
        float s = acc[n];
#pragma unroll
        for (int o = 32; o >= 1; o >>= 1) s += __shfl_xor(s, o, 64);
        if (lane == n) out[(size_t)row * NC_ + n] = s + bias[n];
    }
}

// ---------------------------------------------------------------------------
extern "C" void kernel_launch(void* const* d_in, const int* in_sizes, int n_in,
                              void* d_out, int out_size, void* d_ws, size_t ws_size,
                              hipStream_t stream)
{
    const float* query   = (const float*)d_in[0];
    const float* value   = (const float*)d_in[1];
    const float* refp    = (const float*)d_in[2];
    const float* w_value = (const float*)d_in[3];
    const float* b_value = (const float*)d_in[4];
    const float* w_off   = (const float*)d_in[5];
    const float* b_off   = (const float*)d_in[6];
    const float* w_attn  = (const float*)d_in[7];
    const float* b_attn  = (const float*)d_in[8];
    const float* w_out   = (const float*)d_in[9];
    const float* b_out   = (const float*)d_in[10];
    const float* ln1w    = (const float*)d_in[11];
    const float* ln1b    = (const float*)d_in[12];
    const float* w_ffn1  = (const float*)d_in[13];
    const float* b_ffn1  = (const float*)d_in[14];
    const float* w_ffn2  = (const float*)d_in[15];
    const float* b_ffn2  = (const float*)d_in[16];
    const float* ln2w    = (const float*)d_in[17];
    const float* ln2b    = (const float*)d_in[18];
    const float* w_cls   = (const float*)d_in[19];
    const float* b_cls   = (const float*)d_in[20];

    // ---- workspace layout ----
    short* WvT   = (short*)d_ws;            //  65536
    short* WoaT  = WvT  + 65536;            //  98304 (384x256)
    short* WoutT = WoaT + 98304;            //  65536
    short* Wf1T  = WoutT + 65536;           // 262144 (1024x256)
    short* Wf2T  = Wf1T + 262144;           // 262144 (256x1024)
    float* bias_cat = (float*)(Wf2T + 262144);            // 384
    ushort_t* v = (ushort_t*)(bias_cat + 384);            // [B,M,S,D] bf16, 80 MB
    float* oa   = (float*)(v + (size_t)RV_ * C_);         // [RQ,384]
    float* loc  = oa   + (size_t)RQ_ * 384;               // [RQ,256]
    float* attn = loc  + (size_t)RQ_ * 256;               // [RQ,128]
    float* feat = attn + (size_t)RQ_ * 128;               // [RQ,256]
    float* tmp  = feat + (size_t)RQ_ * 256;               // [RQ,256]
    float* h    = tmp  + (size_t)RQ_ * 256;               // [RQ,1024]
    float* x2   = h    + (size_t)RQ_ * FFN_;              // [RQ,256]

    // 0) weight prep (bf16 + transpose), bias concat
    prep_weights<<<dim3(64, 1, 5), 256, 0, stream>>>(
        w_value, w_off, w_attn, w_out, w_ffn1, w_ffn2,
        WvT, WoaT, WoutT, Wf1T, Wf2T);
    prep_bias<<<1, 384, 0, stream>>>(b_off, b_attn, bias_cat);

    // 1) v = value @ w_value + b_value  -> bf16 [B,M,S,D]
    gemm_mfma<1, 128><<<dim3((RV_ + 127) / 128, 2), 256, 0, stream>>>(
        value, WvT, b_value, nullptr, (float*)v, RV_, 256, 256);

    // 2) fused off|attn logits
    gemm_mfma<0, 64><<<dim3((RQ_ + 63) / 64, 3), 256, 0, stream>>>(
        query, WoaT, bias_cat, nullptr, oa, RQ_, 384, 256);

    // 3) softmax + pixel-coord locations
    softmax_loc_kernel<<<RQ_, 128, 0, stream>>>(oa, refp, loc, attn);

    // 4) deformable sampling -> feat [RQ, C]
    sample_kernel<<<RQ_, 256, 0, stream>>>(v, loc, attn, feat);

    // 5) tmp = query + feat @ w_out + b_out
    gemm_mfma<3, 64><<<dim3((RQ_ + 63) / 64, 2), 256, 0, stream>>>(
        feat, WoutT, b_out, query, tmp, RQ_, 256, 256);

    // 6) x1 = LN(tmp) -> feat reused
    ln_kernel<<<RQ_, 64, 0, stream>>>(tmp, ln1w, ln1b, feat);

    // 7) h = relu(x1 @ w_ffn1 + b_ffn1)
    gemm_mfma<2, 64><<<dim3((RQ_ + 63) / 64, 8), 256, 0, stream>>>(
        feat, Wf1T, b_ffn1, nullptr, h, RQ_, 1024, 256);

    // 8) tmp = x1 + h @ w_ffn2 + b_ffn2
    gemm_mfma<3, 64><<<dim3((RQ_ + 63) / 64, 2), 256, 0, stream>>>(
        h, Wf2T, b_ffn2, feat, tmp, RQ_, 256, 1024);

    // 9) x2 = LN(tmp)
    ln_kernel<<<RQ_, 64, 0, stream>>>(tmp, ln2w, ln2b, x2);

    // 10) out = x2 @ w_cls + b_cls
    cls_kernel<<<RQ_, 64, 0, stream>>>(x2, w_cls, b_cls, (float*)d_out);
}

// Round 4
// 504.769 us; speedup vs baseline: 1.3095x; 1.3095x over previous
//
#include <hip/hip_runtime.h>
#include <cstddef>
#include <cstdint>

// ---------------------------------------------------------------------------
// Problem constants (ImplicitHead2D_Seq_MS_Deform)
// ---------------------------------------------------------------------------
#define B_    8
#define NQ_   900
#define C_    256
#define M_    8
#define P_    4
#define L_    4
#define D_    32
#define S_    19560
#define NC_   10
#define FFN_  1024
#define RQ_   (B_ * NQ_)   // 7200 query rows
#define RV_   (B_ * S_)    // 156480 value rows

typedef __attribute__((ext_vector_type(8))) short bf8_t;           // 8 x bf16
typedef __attribute__((ext_vector_type(8))) unsigned short us8_t;  // 8 x u16
typedef __attribute__((ext_vector_type(4))) float f4_t;            // 4 x f32
typedef unsigned short ushort_t;

__device__ __forceinline__ unsigned short f2bf(float x) {
    union { float f; unsigned u; } v; v.f = x;
    unsigned r = v.u + 0x7FFF + ((v.u >> 16) & 1);   // round-nearest-even
    return (unsigned short)(r >> 16);
}
__device__ __forceinline__ float bfu2f(unsigned short u) {
    union { unsigned u; float f; } v; v.u = ((unsigned)u) << 16; return v.f;
}

// ---------------------------------------------------------------------------
// Weight prep: fp32 W[K][N] -> bf16 W^T[N][K].  64x64 tiles via LDS.
// ---------------------------------------------------------------------------
__global__ __launch_bounds__(256) void prep_weights(
    const float* __restrict__ w_value, const float* __restrict__ w_off,
    const float* __restrict__ w_attn,  const float* __restrict__ w_out,
    const float* __restrict__ w_ffn1,  const float* __restrict__ w_ffn2,
    short* __restrict__ WvT, short* __restrict__ WoaT, short* __restrict__ WoutT,
    short* __restrict__ Wf1T, short* __restrict__ Wf2T)
{
    const int mat = blockIdx.z;
    int K, N; const float* src; short* dst;
    switch (mat) {
        case 0: K = 256;  N = 256;  src = w_value; dst = WvT;  break;
        case 1: K = 256;  N = 384;  src = nullptr; dst = WoaT; break;
        case 2: K = 256;  N = 256;  src = w_out;   dst = WoutT; break;
        case 3: K = 256;  N = 1024; src = w_ffn1;  dst = Wf1T; break;
        default:K = 1024; N = 256;  src = w_ffn2;  dst = Wf2T; break;
    }
    const int ntn = N >> 6;
    const int kt = blockIdx.x / ntn, nt = blockIdx.x % ntn;
    if (kt >= (K >> 6)) return;

    __shared__ float t[64][65];
    const int tx = threadIdx.x & 63;
    const int ty = threadIdx.x >> 6;
#pragma unroll
    for (int i = 0; i < 64; i += 4) {
        const int k = kt * 64 + i + ty;
        const int n = nt * 64 + tx;
        float v;
        if (mat == 1) v = (n < 256) ? w_off[(size_t)k * 256 + n]
                                    : w_attn[(size_t)k * 128 + (n - 256)];
        else          v = src[(size_t)k * N + n];
        t[i + ty][tx] = v;
    }
    __syncthreads();
#pragma unroll
    for (int i = 0; i < 64; i += 4) {
        const int n = nt * 64 + i + ty;
        const int k = kt * 64 + tx;
        dst[(size_t)n * K + k] = (short)f2bf(t[tx][i + ty]);
    }
}

__global__ __launch_bounds__(384) void prep_bias(
    const float* __restrict__ b_off, const float* __restrict__ b_attn,
    float* __restrict__ bias_cat)
{
    const int t = threadIdx.x;
    bias_cat[t] = (t < 256) ? b_off[t] : b_attn[t - 256];
}

// ---------------------------------------------------------------------------
// bf16 MFMA GEMM, register-double-buffered K pipeline.
//  out[R,N] = A[R,K](fp32) @ WT(bf16 [N][K]) + bias
//  MODE 0: plain fp32   MODE 1: bf16 value-permute -> v[B,M,S,D] (BM=128 only)
//  MODE 2: relu fp32    MODE 3: residual fp32 (+res[r*N+n])
//  BM in {128, 64}; BN=128; BK=64; 4 waves (2x2), wave tile (BM/2)x64.
//  LDS XOR-swizzled on 16B units (u ^ (row&7)) for conflict-free ds_read_b128.
// ---------------------------------------------------------------------------
template <int MODE, int BM>
__global__ __launch_bounds__(256) void gemm_mfma(
    const float* __restrict__ A, const short* __restrict__ WT,
    const float* __restrict__ bias, const float* __restrict__ res,
    float* __restrict__ out, int R, int N, int K)
{
    constexpr int NI  = BM / 32;          // acc rows per wave (4 or 2)
    constexpr int AIT = BM * 8 / 256;     // A staging iters (4 or 2)
    constexpr int ASB = BM * 128;         // As bytes
    constexpr int SMEM_BYTES = (MODE == 1) ? (128 * 136 * 2) : (ASB + 16384);

    __shared__ __align__(16) char smem[SMEM_BYTES];
    short* As = (short*)smem;             // [BM][64] swizzled
    short* Bs = (short*)(smem + ASB);     // [128][64] swizzled

    const int tid  = threadIdx.x;
    const int lane = tid & 63;
    const int wave = tid >> 6;
    const int wr   = wave >> 1;
    const int wc   = wave & 1;
    const int g    = lane >> 4;           // 0..3
    const int fr   = lane & 15;

    const int row0 = blockIdx.x * BM;
    const int col0 = blockIdx.y * 128;

    const int r_base = tid >> 3;          // 0..31
    const int ku     = tid & 7;           // 0..7 (8-elem k-chunk)

    float4 rA[AIT][2];
#pragma unroll
    for (int it = 0; it < AIT; ++it) {
        rA[it][0] = make_float4(0.f, 0.f, 0.f, 0.f);
        rA[it][1] = make_float4(0.f, 0.f, 0.f, 0.f);
    }
    int4 rB[4];

    f4_t acc[NI][4] = {};

    auto LOAD = [&](int k0) {
#pragma unroll
        for (int it = 0; it < AIT; ++it) {
            const int grow = row0 + it * 32 + r_base;
            if (grow < R) {
                rA[it][0] = *(const float4*)(A + (size_t)grow * K + k0 + ku * 8);
                rA[it][1] = *(const float4*)(A + (size_t)grow * K + k0 + ku * 8 + 4);
            }
        }
#pragma unroll
        for (int it = 0; it < 4; ++it) {
            const int n = it * 32 + r_base;
            rB[it] = *(const int4*)(WT + (size_t)(col0 + n) * K + k0 + ku * 8);
        }
    };
    auto WRITE = [&]() {
#pragma unroll
        for (int it = 0; it < AIT; ++it) {
            const int r = it * 32 + r_base;
            const float va[8] = {rA[it][0].x, rA[it][0].y, rA[it][0].z, rA[it][0].w,
                                 rA[it][1].x, rA[it][1].y, rA[it][1].z, rA[it][1].w};
            bf8_t pk;
#pragma unroll
            for (int j = 0; j < 8; ++j) pk[j] = (short)f2bf(va[j]);
            *(bf8_t*)&As[r * 64 + (ku ^ (r & 7)) * 8] = pk;
        }
#pragma unroll
        for (int it = 0; it < 4; ++it) {
            const int n = it * 32 + r_base;
            *(int4*)&Bs[n * 64 + (ku ^ (n & 7)) * 8] = rB[it];
        }
    };

    LOAD(0);
    for (int k0 = 0; k0 < K; k0 += 64) {
        WRITE();
        __syncthreads();
        if (k0 + 64 < K) LOAD(k0 + 64);   // in flight during MFMA phase
#pragma unroll
        for (int c = 0; c < 2; ++c) {
            bf8_t fa[NI], fb[4];
#pragma unroll
            for (int i = 0; i < NI; ++i) {
                const int ar = wr * (BM / 2) + i * 16 + fr;
                fa[i] = *(const bf8_t*)&As[ar * 64 + ((c * 4 + g) ^ (ar & 7)) * 8];
            }
#pragma unroll
            for (int j = 0; j < 4; ++j) {
                const int br = wc * 64 + j * 16 + fr;
                fb[j] = *(const bf8_t*)&Bs[br * 64 + ((c * 4 + g) ^ (br & 7)) * 8];
            }
#pragma unroll
            for (int i = 0; i < NI; ++i)
#pragma unroll
                for (int j = 0; j < 4; ++j)
                    acc[i][j] = __builtin_amdgcn_mfma_f32_16x16x32_bf16(
                        fa[i], fb[j], acc[i][j], 0, 0, 0);
        }
        __syncthreads();
    }

    // ---- epilogue ----  D layout: col = lane&15 -> fr, row = g*4 + reg
    if (MODE == 1) {
        // bf16 value-permute epilogue via LDS repack -> coalesced 16B stores
        ushort_t* eps = (ushort_t*)smem;   // [128][136]
        ushort_t* outv = (ushort_t*)out;
#pragma unroll
        for (int j = 0; j < 4; ++j) {
            const int col_l = wc * 64 + j * 16 + fr;
            const float bcol = bias[col0 + col_l];
#pragma unroll
            for (int i = 0; i < NI; ++i)
#pragma unroll
                for (int r = 0; r < 4; ++r) {
                    const int row_l = wr * 64 + i * 16 + g * 4 + r;
                    eps[row_l * 136 + col_l] = f2bf(acc[i][j][r] + bcol);
                }
        }
        __syncthreads();
#pragma unroll
        for (int u = 0; u < 8; ++u) {
            const int unit = u * 256 + tid;
            const int sl = unit >> 4;         // 0..127 local row
            const int cc = unit & 15;         // 16B chunk
            const int grow = row0 + sl;
            if (grow < R) {
                const int b = grow / S_;
                const int s = grow - b * S_;
                const int col = col0 + cc * 8;
                const int m = col >> 5;
                const int d = col & 31;
                const int4 w = *(const int4*)&eps[sl * 136 + cc * 8];
                *(int4*)&outv[(((size_t)(b * M_ + m)) * S_ + s) * D_ + d] = w;
            }
        }
    } else {
#pragma unroll
        for (int j = 0; j < 4; ++j) {
            const int col = col0 + wc * 64 + j * 16 + fr;
            const float bcol = bias[col];
#pragma unroll
            for (int i = 0; i < NI; ++i) {
#pragma unroll
                for (int r = 0; r < 4; ++r) {
                    const int row = row0 + wr * (BM / 2) + i * 16 + g * 4 + r;
                    if (row >= R) continue;
                    float vv = acc[i][j][r] + bcol;
                    if (MODE == 2) {
                        out[(size_t)row * N + col] = fmaxf(vv, 0.f);
                    } else if (MODE == 3) {
                        out[(size_t)row * N + col] = vv + res[(size_t)row * N + col];
                    } else {
                        out[(size_t)row * N + col] = vv;
                    }
                }
            }
        }
    }
}

// ---------------------------------------------------------------------------
// Softmax over L*P=16 per head + bake sampling locations to pixel coords.
// oa row: [0..255] off (m*32+l*8+p*2+c), [256..383] attn logits (m*16+l*4+p).
// ---------------------------------------------------------------------------
__global__ __launch_bounds__(128) void softmax_loc_kernel(
    const float* __restrict__ oa, const float* __restrict__ ref,
    float* __restrict__ loc, float* __restrict__ attn)
{
    const int row = blockIdx.x;
    const int t   = threadIdx.x;       // 0..127 (m = t>>4)
    const float Wtab[L_] = {160.f, 80.f, 40.f, 20.f};
    const float Htab[L_] = {92.f, 46.f, 23.f, 12.f};

    float vlog = oa[(size_t)row * 384 + 256 + t];
    float mx = vlog;
#pragma unroll
    for (int o = 8; o >= 1; o >>= 1) mx = fmaxf(mx, __shfl_xor(mx, o, 64));
    const float e = __expf(vlog - mx);
    float sm = e;
#pragma unroll
    for (int o = 8; o >= 1; o >>= 1) sm += __shfl_xor(sm, o, 64);
    attn[(size_t)row * 128 + t] = e / sm;

    const int m = t >> 4, l = (t >> 2) & 3, p = t & 3;
    const float rx = ref[(size_t)row * 2 + 0];
    const float ry = ref[(size_t)row * 2 + 1];
    const int oi = m * 32 + l * 8 + p * 2;
    loc[(size_t)row * 256 + oi + 0] = rx * Wtab[l] + oa[(size_t)row * 384 + oi + 0] - 0.5f;
    loc[(size_t)row * 256 + oi + 1] = ry * Htab[l] + oa[(size_t)row * 384 + oi + 1] - 0.5f;
}

// ---------------------------------------------------------------------------
// Deformable sampling, bf16 v, vectorized: thread = (rl = t>>5, m = (t>>2)&7,
// dg = t&3); each thread computes 8 channels (d = dg*8 .. dg*8+7) for all 16
// points of its (row, m) via 16B ushort8 corner loads. 8 rows per block.
// Branch-free: clamped indices + validity-zeroed weights.
// LDS: padded [8][8][33]/[8][8][17] so the 8 m's read from 8 distinct banks.
// ---------------------------------------------------------------------------
__global__ __launch_bounds__(256) void sample_kernel(
    const ushort_t* __restrict__ v, const float* __restrict__ loc,
    const float* __restrict__ attn, float* __restrict__ outf)
{
    const int row0 = blockIdx.x * 8;
    const int t    = threadIdx.x;
    const int rl   = t >> 5;          // 0..7
    const int m    = (t >> 2) & 7;    // 0..7
    const int dg   = t & 3;           // 0..3

    __shared__ float sloc[8][8][33];
    __shared__ float satt[8][8][17];

    // stage loc: 8 rows x 256 floats = 512 float4, 2 per thread
    {
        const float4* src = (const float4*)(loc + (size_t)row0 * 256);
#pragma unroll
        for (int i = 0; i < 2; ++i) {
            const int u   = i * 256 + t;        // 0..511
            const int r_  = u >> 6;
            const int rem = u & 63;
            const int m_  = rem >> 3;
            const int c4  = (rem & 7) * 4;
            *(float4*)&sloc[r_][m_][c4] = src[u];
        }
        // stage attn: 8 rows x 128 floats = 256 float4, 1 per thread
        const float4* asrc = (const float4*)(attn + (size_t)row0 * 128);
        {
            const int u   = t;
            const int r_  = u >> 5;
            const int rem = u & 31;
            const int m_  = rem >> 2;
            const int c4  = (rem & 3) * 4;
            *(float4*)&satt[r_][m_][c4] = asrc[u];
        }
    }
    __syncthreads();

    const int row = row0 + rl;
    const int b   = row / NQ_;
    const ushort_t* vbase = v + (((size_t)(b * M_ + m)) * S_) * D_ + dg * 8;

    const int Wtab[L_] = {160, 80, 40, 20};
    const int Htab[L_] = {92, 46, 23, 12};
    const int Stab[L_] = {0, 14720, 18400, 19320};

    float acc[8] = {};

#pragma unroll
    for (int l = 0; l < L_; ++l) {
        const int Wl = Wtab[l], Hl = Htab[l], st = Stab[l];
#pragma unroll
        for (int p = 0; p < P_; ++p) {
            const float x = sloc[rl][m][l * 8 + p * 2 + 0];
            const float y = sloc[rl][m][l * 8 + p * 2 + 1];
            const float a = satt[rl][m][l * 4 + p];
            const float xf = floorf(x), yf = floorf(y);
            const int x0 = (int)xf, y0 = (int)yf;
            const float lx = x - xf, ly = y - yf;
            // validity-zeroed axis weights
            const float wx0 = (x0 >= 0 && x0 < Wl)         ? (1.f - lx) : 0.f;
            const float wx1 = (x0 + 1 >= 0 && x0 + 1 < Wl) ? lx         : 0.f;
            const float wy0 = (y0 >= 0 && y0 < Hl)         ? (1.f - ly) : 0.f;
            const float wy1 = (y0 + 1 >= 0 && y0 + 1 < Hl) ? ly         : 0.f;
            const float ay0 = a * wy0, ay1 = a * wy1;
            const float aw00 = ay0 * wx0, aw01 = ay0 * wx1;
            const float aw10 = ay1 * wx0, aw11 = ay1 * wx1;
            // clamped indices (loads always safe)
            const int xc0 = min(max(x0, 0), Wl - 1);
            const int xc1 = min(max(x0 + 1, 0), Wl - 1);
            const int yc0 = min(max(y0, 0), Hl - 1);
            const int yc1 = min(max(y0 + 1, 0), Hl - 1);
            const us8_t s00 = *(const us8_t*)(vbase + (size_t)(st + yc0 * Wl + xc0) * D_);
            const us8_t s01 = *(const us8_t*)(vbase + (size_t)(st + yc0 * Wl + xc1) * D_);
            const us8_t s10 = *(const us8_t*)(vbase + (size_t)(st + yc1 * Wl + xc0) * D_);
            const us8_t s11 = *(const us8_t*)(vbase + (size_t)(st + yc1 * Wl + xc1) * D_);
#pragma unroll
            for (int j = 0; j < 8; ++j)
                acc[j] += aw00 * bfu2f(s00[j]) + aw01 * bfu2f(s01[j])
                        + aw10 * bfu2f(s10[j]) + aw11 * bfu2f(s11[j]);
        }
    }

    float* o = outf + (size_t)row * 256 + m * 32 + dg * 8;
    *(float4*)o       = make_float4(acc[0], acc[1], acc[2], acc[3]);
    *((float4*)o + 1) = make_float4(acc[4], acc[5], acc[6], acc[7]);
}

// ---------------------------------------------------------------------------
// LayerNorm over C=256. grid = 7200, block = 64 (one wave), float4 per lane.
// ---------------------------------------------------------------------------
__global__ __launch_bounds__(64) void ln_kernel(
    const float* __restrict__ in, const float* __restrict__ w,
    const float* __restrict__ bp, float* __restrict__ out)
{
    const int row  = blockIdx.x;
    const int lane = threadIdx.x;
    const float4 x = ((const float4*)(in + (size_t)row * C_))[lane];
    float s = x.x + x.y + x.z + x.w;
#pragma unroll
    for (int o = 32; o >= 1; o >>= 1) s += __shfl_xor(s, o, 64);
    const float mean = s * (1.f / C_);
    const float d0 = x.x - mean, d1 = x.y - mean, d2 = x.z - mean, d3 = x.w - mean;
    float ss = d0 * d0 + d1 * d1 + d2 * d2 + d3 * d3;
#pragma unroll
    for (int o = 32; o >= 1; o >>= 1) ss += __shfl_xor(ss, o, 64);
    const float r = rsqrtf(ss * (1.f / C_) + 1e-6f);
    const float4 wv = ((const float4*)w)[lane];
    const float4 bv = ((const float4*)bp)[lane];
    float4 o4;
    o4.x = d0 * r * wv.x + bv.x;
    o4.y = d1 * r * wv.y + bv.y;
    o4.z = d2 * r * wv.z + bv.z;
    o4.w = d3 * r * wv.w + bv.w;
    ((float4*)(out + (size_t)row * C_))[lane] = o4;
}

// ---------------------------------------------------------------------------
// Classifier head: out[row,0..9] = x[row,:] @ w_cls + b_cls. grid=7200, block=64.
// ---------------------------------------------------------------------------
__global__ __launch_bounds__(64) void cls_kernel(
    const float* __restrict__ x, const float* __restrict__ w,
    const float* __restrict__ bias, float* __restrict__ out)
{
    const int row  = blockIdx.x;
    const int lane = threadIdx.x;
    float acc[NC_] = {};
#pragma unroll
    for (int j = 0; j < 4; ++j) {
        const int k = lane + j * 64;
        const float xk = x[(size_t)row * C_ + k];
        const float* wr = w + (size_t)k * NC_;
#pragma unroll
        for (int n = 0; n < NC_; ++n) acc[n] += xk * wr[n];
    }
#pragma unroll
    for (int n = 0; n < NC_; ++n) {
        float s = acc[n];
#pragma unroll
        for (int o = 32; o >= 1; o >>= 1) s += __shfl_xor(s, o, 64);
        if (lane == n) out[(size_t)row * NC_ + n] = s + bias[n];
    }
}

// ---------------------------------------------------------------------------
extern "C" void kernel_launch(void* const* d_in, const int* in_sizes, int n_in,
                              void* d_out, int out_size, void* d_ws, size_t ws_size,
                              hipStream_t stream)
{
    const float* query   = (const float*)d_in[0];
    const float* value   = (const float*)d_in[1];
    const float* refp    = (const float*)d_in[2];
    const float* w_value = (const float*)d_in[3];
    const float* b_value = (const float*)d_in[4];
    const float* w_off   = (const float*)d_in[5];
    const float* b_off   = (const float*)d_in[6];
    const float* w_attn  = (const float*)d_in[7];
    const float* b_attn  = (const float*)d_in[8];
    const float* w_out   = (const float*)d_in[9];
    const float* b_out   = (const float*)d_in[10];
    const float* ln1w    = (const float*)d_in[11];
    const float* ln1b    = (const float*)d_in[12];
    const float* w_ffn1  = (const float*)d_in[13];
    const float* b_ffn1  = (const float*)d_in[14];
    const float* w_ffn2  = (const float*)d_in[15];
    const float* b_ffn2  = (const float*)d_in[16];
    const float* ln2w    = (const float*)d_in[17];
    const float* ln2b    = (const float*)d_in[18];
    const float* w_cls   = (const float*)d_in[19];
    const float* b_cls   = (const float*)d_in[20];

    // ---- workspace layout ----
    short* WvT   = (short*)d_ws;            //  65536
    short* WoaT  = WvT  + 65536;            //  98304 (384x256)
    short* WoutT = WoaT + 98304;            //  65536
    short* Wf1T  = WoutT + 65536;           // 262144 (1024x256)
    short* Wf2T  = Wf1T + 262144;           // 262144 (256x1024)
    float* bias_cat = (float*)(Wf2T + 262144);            // 384
    ushort_t* v = (ushort_t*)(bias_cat + 384);            // [B,M,S,D] bf16, 80 MB
    float* oa   = (float*)(v + (size_t)RV_ * C_);         // [RQ,384]
    float* loc  = oa   + (size_t)RQ_ * 384;               // [RQ,256]
    float* attn = loc  + (size_t)RQ_ * 256;               // [RQ,128]
    float* feat = attn + (size_t)RQ_ * 128;               // [RQ,256]
    float* tmp  = feat + (size_t)RQ_ * 256;               // [RQ,256]
    float* h    = tmp  + (size_t)RQ_ * 256;               // [RQ,1024]
    float* x2   = h    + (size_t)RQ_ * FFN_;              // [RQ,256]

    // 0) weight prep (bf16 + transpose), bias concat
    prep_weights<<<dim3(64, 1, 5), 256, 0, stream>>>(
        w_value, w_off, w_attn, w_out, w_ffn1, w_ffn2,
        WvT, WoaT, WoutT, Wf1T, Wf2T);
    prep_bias<<<1, 384, 0, stream>>>(b_off, b_attn, bias_cat);

    // 1) v = value @ w_value + b_value  -> bf16 [B,M,S,D]
    gemm_mfma<1, 128><<<dim3((RV_ + 127) / 128, 2), 256, 0, stream>>>(
        value, WvT, b_value, nullptr, (float*)v, RV_, 256, 256);

    // 2) fused off|attn logits
    gemm_mfma<0, 64><<<dim3((RQ_ + 63) / 64, 3), 256, 0, stream>>>(
        query, WoaT, bias_cat, nullptr, oa, RQ_, 384, 256);

    // 3) softmax + pixel-coord locations
    softmax_loc_kernel<<<RQ_, 128, 0, stream>>>(oa, refp, loc, attn);

    // 4) deformable sampling -> feat [RQ, C]
    sample_kernel<<<RQ_ / 8, 256, 0, stream>>>(v, loc, attn, feat);

    // 5) tmp = query + feat @ w_out + b_out
    gemm_mfma<3, 64><<<dim3((RQ_ + 63) / 64, 2), 256, 0, stream>>>(
        feat, WoutT, b_out, query, tmp, RQ_, 256, 256);

    // 6) x1 = LN(tmp) -> feat reused
    ln_kernel<<<RQ_, 64, 0, stream>>>(tmp, ln1w, ln1b, feat);

    // 7) h = relu(x1 @ w_ffn1 + b_ffn1)
    gemm_mfma<2, 64><<<dim3((RQ_ + 63) / 64, 8), 256, 0, stream>>>(
        feat, Wf1T, b_ffn1, nullptr, h, RQ_, 1024, 256);

    // 8) tmp = x1 + h @ w_ffn2 + b_ffn2
    gemm_mfma<3, 64><<<dim3((RQ_ + 63) / 64, 2), 256, 0, stream>>>(
        h, Wf2T, b_ffn2, feat, tmp, RQ_, 256, 1024);

    // 9) x2 = LN(tmp)
    ln_kernel<<<RQ_, 64, 0, stream>>>(tmp, ln2w, ln2b, x2);

    // 10) out = x2 @ w_cls + b_cls
    cls_kernel<<<RQ_, 64, 0, stream>>>(x2, w_cls, b_cls, (float*)d_out);
}

// Round 5
// 493.629 us; speedup vs baseline: 1.3390x; 1.0226x over previous
//
#include <hip/hip_runtime.h>
#include <cstddef>
#include <cstdint>

// ---------------------------------------------------------------------------
// Problem constants (ImplicitHead2D_Seq_MS_Deform)
// ---------------------------------------------------------------------------
#define B_    8
#define NQ_   900
#define C_    256
#define M_    8
#define P_    4
#define L_    4
#define D_    32
#define S_    19560
#define NC_   10
#define FFN_  1024
#define RQ_   (B_ * NQ_)   // 7200 query rows
#define RV_   (B_ * S_)    // 156480 value rows

typedef __attribute__((ext_vector_type(8))) short bf8_t;           // 8 x bf16
typedef __attribute__((ext_vector_type(8))) unsigned short us8_t;  // 8 x u16
typedef __attribute__((ext_vector_type(4))) float f4_t;            // 4 x f32
typedef unsigned short ushort_t;

__device__ __forceinline__ unsigned short f2bf(float x) {
    union { float f; unsigned u; } v; v.f = x;
    unsigned r = v.u + 0x7FFF + ((v.u >> 16) & 1);   // round-nearest-even
    return (unsigned short)(r >> 16);
}
__device__ __forceinline__ float bfu2f(unsigned short u) {
    union { unsigned u; float f; } v; v.u = ((unsigned)u) << 16; return v.f;
}

// ---------------------------------------------------------------------------
// Weight prep: fp32 W[K][N] -> bf16 W^T[N][K].  64x64 tiles via LDS.
// ---------------------------------------------------------------------------
__global__ __launch_bounds__(256) void prep_weights(
    const float* __restrict__ w_value, const float* __restrict__ w_off,
    const float* __restrict__ w_attn,  const float* __restrict__ w_out,
    const float* __restrict__ w_ffn1,  const float* __restrict__ w_ffn2,
    short* __restrict__ WvT, short* __restrict__ WoaT, short* __restrict__ WoutT,
    short* __restrict__ Wf1T, short* __restrict__ Wf2T)
{
    const int mat = blockIdx.z;
    int K, N; const float* src; short* dst;
    switch (mat) {
        case 0: K = 256;  N = 256;  src = w_value; dst = WvT;  break;
        case 1: K = 256;  N = 384;  src = nullptr; dst = WoaT; break;
        case 2: K = 256;  N = 256;  src = w_out;   dst = WoutT; break;
        case 3: K = 256;  N = 1024; src = w_ffn1;  dst = Wf1T; break;
        default:K = 1024; N = 256;  src = w_ffn2;  dst = Wf2T; break;
    }
    const int ntn = N >> 6;
    const int kt = blockIdx.x / ntn, nt = blockIdx.x % ntn;
    if (kt >= (K >> 6)) return;

    __shared__ float t[64][65];
    const int tx = threadIdx.x & 63;
    const int ty = threadIdx.x >> 6;
#pragma unroll
    for (int i = 0; i < 64; i += 4) {
        const int k = kt * 64 + i + ty;
        const int n = nt * 64 + tx;
        float v;
        if (mat == 1) v = (n < 256) ? w_off[(size_t)k * 256 + n]
                                    : w_attn[(size_t)k * 128 + (n - 256)];
        else          v = src[(size_t)k * N + n];
        t[i + ty][tx] = v;
    }
    __syncthreads();
#pragma unroll
    for (int i = 0; i < 64; i += 4) {
        const int n = nt * 64 + i + ty;
        const int k = kt * 64 + tx;
        dst[(size_t)n * K + k] = (short)f2bf(t[tx][i + ty]);
    }
}

__global__ __launch_bounds__(384) void prep_bias(
    const float* __restrict__ b_off, const float* __restrict__ b_attn,
    float* __restrict__ bias_cat)
{
    const int t = threadIdx.x;
    bias_cat[t] = (t < 256) ? b_off[t] : b_attn[t - 256];
}

// ---------------------------------------------------------------------------
// Value-projection GEMM, specialized: v[B,M,S,D](bf16) = value[RV,256] @ WvT.
// BM=128, BN=256 (full width -> each A-row fetched ONCE), BK=64.
// 512 threads = 8 waves (2 row x 4 col), wave tile 64x64, 16x16x32 bf16 MFMA.
// LDS: As[128][64] (16KB) + Bs[256][64] (32KB), XOR-swizzled 16B units.
// Register prefetch of K-step k+1 during MFMA of step k.
// Epilogue: two 128-col LDS-repack passes -> coalesced 16B bf16 stores.
// ---------------------------------------------------------------------------
__global__ __launch_bounds__(512, 4) void gemm_value(
    const float* __restrict__ A, const short* __restrict__ WT,
    const float* __restrict__ bias, ushort_t* __restrict__ outv, int R)
{
    __shared__ __align__(16) char smem[49152];
    short* As = (short*)smem;             // [128][64] swizzled
    short* Bs = (short*)(smem + 16384);   // [256][64] swizzled

    const int tid  = threadIdx.x;
    const int lane = tid & 63;
    const int wave = tid >> 6;        // 0..7
    const int wr   = wave >> 2;       // 0..1
    const int wc   = wave & 3;        // 0..3
    const int g    = lane >> 4;       // 0..3
    const int fr   = lane & 15;

    const int row0 = blockIdx.x * 128;

    const int r_base = tid >> 3;      // 0..63
    const int ku     = tid & 7;       // 0..7

    float4 rA[2][2];
#pragma unroll
    for (int it = 0; it < 2; ++it) {
        rA[it][0] = make_float4(0.f, 0.f, 0.f, 0.f);
        rA[it][1] = make_float4(0.f, 0.f, 0.f, 0.f);
    }
    int4 rB[4];
    f4_t acc[4][4] = {};

    auto LOAD = [&](int k0) {
#pragma unroll
        for (int it = 0; it < 2; ++it) {
            const int grow = row0 + it * 64 + r_base;
            if (grow < R) {
                rA[it][0] = *(const float4*)(A + (size_t)grow * 256 + k0 + ku * 8);
                rA[it][1] = *(const float4*)(A + (size_t)grow * 256 + k0 + ku * 8 + 4);
            }
        }
#pragma unroll
        for (int it = 0; it < 4; ++it) {
            const int n = it * 64 + r_base;
            rB[it] = *(const int4*)(WT + (size_t)n * 256 + k0 + ku * 8);
        }
    };
    auto WRITE = [&]() {
#pragma unroll
        for (int it = 0; it < 2; ++it) {
            const int r = it * 64 + r_base;
            const float va[8] = {rA[it][0].x, rA[it][0].y, rA[it][0].z, rA[it][0].w,
                                 rA[it][1].x, rA[it][1].y, rA[it][1].z, rA[it][1].w};
            bf8_t pk;
#pragma unroll
            for (int j = 0; j < 8; ++j) pk[j] = (short)f2bf(va[j]);
            *(bf8_t*)&As[r * 64 + (ku ^ (r & 7)) * 8] = pk;
        }
#pragma unroll
        for (int it = 0; it < 4; ++it) {
            const int n = it * 64 + r_base;
            *(int4*)&Bs[n * 64 + (ku ^ (n & 7)) * 8] = rB[it];
        }
    };

    LOAD(0);
    for (int k0 = 0; k0 < 256; k0 += 64) {
        WRITE();
        __syncthreads();
        if (k0 + 64 < 256) LOAD(k0 + 64);   // in flight during MFMA phase
#pragma unroll
        for (int c = 0; c < 2; ++c) {
            bf8_t fa[4], fb[4];
#pragma unroll
            for (int i = 0; i < 4; ++i) {
                const int ar = wr * 64 + i * 16 + fr;
                fa[i] = *(const bf8_t*)&As[ar * 64 + ((c * 4 + g) ^ (ar & 7)) * 8];
            }
#pragma unroll
            for (int j = 0; j < 4; ++j) {
                const int br = wc * 64 + j * 16 + fr;
                fb[j] = *(const bf8_t*)&Bs[br * 64 + ((c * 4 + g) ^ (br & 7)) * 8];
            }
#pragma unroll
            for (int i = 0; i < 4; ++i)
#pragma unroll
                for (int j = 0; j < 4; ++j)
                    acc[i][j] = __builtin_amdgcn_mfma_f32_16x16x32_bf16(
                        fa[i], fb[j], acc[i][j], 0, 0, 0);
        }
        __syncthreads();
    }

    // ---- epilogue: two 128-col repack passes through LDS ----
    // D layout: col = lane&15 (fr), row = g*4 + reg
    ushort_t* eps = (ushort_t*)smem;     // [128][136]
    for (int h = 0; h < 2; ++h) {
        __syncthreads();
        if ((wc >> 1) == h) {
            const int wcl = wc & 1;
#pragma unroll
            for (int j = 0; j < 4; ++j) {
                const int col_l = wcl * 64 + j * 16 + fr;
                const float bcol = bias[h * 128 + col_l];
#pragma unroll
                for (int i = 0; i < 4; ++i)
#pragma unroll
                    for (int r = 0; r < 4; ++r) {
                        const int row_l = wr * 64 + i * 16 + g * 4 + r;
                        eps[row_l * 136 + col_l] = f2bf(acc[i][j][r] + bcol);
                    }
            }
        }
        __syncthreads();
#pragma unroll
        for (int u = 0; u < 4; ++u) {
            const int unit = u * 512 + tid;   // 0..2047
            const int sl = unit >> 4;         // 0..127
            const int cc = unit & 15;         // 16B chunk
            const int grow = row0 + sl;
            if (grow < R) {
                const int b = grow / S_;
                const int s = grow - b * S_;
                const int col = h * 128 + cc * 8;
                const int m = col >> 5;
                const int d = col & 31;
                *(int4*)&outv[(((size_t)(b * M_ + m)) * S_ + s) * D_ + d] =
                    *(const int4*)&eps[sl * 136 + cc * 8];
            }
        }
    }
}

// ---------------------------------------------------------------------------
// bf16 MFMA GEMM (query-side), register-prefetched K pipeline.
//  out[R,N] = A[R,K](fp32) @ WT(bf16 [N][K]) + bias
//  MODE 0: plain fp32   MODE 2: relu fp32   MODE 3: residual fp32
//  BM=64; BN=128; BK=64; 4 waves (2x2), wave tile 32x64.
// ---------------------------------------------------------------------------
template <int MODE, int BM>
__global__ __launch_bounds__(256) void gemm_mfma(
    const float* __restrict__ A, const short* __restrict__ WT,
    const float* __restrict__ bias, const float* __restrict__ res,
    float* __restrict__ out, int R, int N, int K)
{
    constexpr int NI  = BM / 32;          // acc rows per wave
    constexpr int AIT = BM * 8 / 256;     // A staging iters
    constexpr int ASB = BM * 128;         // As bytes
    constexpr int SMEM_BYTES = ASB + 16384;

    __shared__ __align__(16) char smem[SMEM_BYTES];
    short* As = (short*)smem;             // [BM][64] swizzled
    short* Bs = (short*)(smem + ASB);     // [128][64] swizzled

    const int tid  = threadIdx.x;
    const int lane = tid & 63;
    const int wave = tid >> 6;
    const int wr   = wave >> 1;
    const int wc   = wave & 1;
    const int g    = lane >> 4;           // 0..3
    const int fr   = lane & 15;

    const int row0 = blockIdx.x * BM;
    const int col0 = blockIdx.y * 128;

    const int r_base = tid >> 3;          // 0..31
    const int ku     = tid & 7;           // 0..7 (8-elem k-chunk)

    float4 rA[AIT][2];
#pragma unroll
    for (int it = 0; it < AIT; ++it) {
        rA[it][0] = make_float4(0.f, 0.f, 0.f, 0.f);
        rA[it][1] = make_float4(0.f, 0.f, 0.f, 0.f);
    }
    int4 rB[4];

    f4_t acc[NI][4] = {};

    auto LOAD = [&](int k0) {
#pragma unroll
        for (int it = 0; it < AIT; ++it) {
            const int grow = row0 + it * 32 + r_base;
            if (grow < R) {
                rA[it][0] = *(const float4*)(A + (size_t)grow * K + k0 + ku * 8);
                rA[it][1] = *(const float4*)(A + (size_t)grow * K + k0 + ku * 8 + 4);
            }
        }
#pragma unroll
        for (int it = 0; it < 4; ++it) {
            const int n = it * 32 + r_base;
            rB[it] = *(const int4*)(WT + (size_t)(col0 + n) * K + k0 + ku * 8);
        }
    };
    auto WRITE = [&]() {
#pragma unroll
        for (int it = 0; it < AIT; ++it) {
            const int r = it * 32 + r_base;
            const float va[8] = {rA[it][0].x, rA[it][0].y, rA[it][0].z, rA[it][0].w,
                                 rA[it][1].x, rA[it][1].y, rA[it][1].z, rA[it][1].w};
            bf8_t pk;
#pragma unroll
            for (int j = 0; j < 8; ++j) pk[j] = (short)f2bf(va[j]);
            *(bf8_t*)&As[r * 64 + (ku ^ (r & 7)) * 8] = pk;
        }
#pragma unroll
        for (int it = 0; it < 4; ++it) {
            const int n = it * 32 + r_base;
            *(int4*)&Bs[n * 64 + (ku ^ (n & 7)) * 8] = rB[it];
        }
    };

    LOAD(0);
    for (int k0 = 0; k0 < K; k0 += 64) {
        WRITE();
        __syncthreads();
        if (k0 + 64 < K) LOAD(k0 + 64);   // in flight during MFMA phase
#pragma unroll
        for (int c = 0; c < 2; ++c) {
            bf8_t fa[NI], fb[4];
#pragma unroll
            for (int i = 0; i < NI; ++i) {
                const int ar = wr * (BM / 2) + i * 16 + fr;
                fa[i] = *(const bf8_t*)&As[ar * 64 + ((c * 4 + g) ^ (ar & 7)) * 8];
            }
#pragma unroll
            for (int j = 0; j < 4; ++j) {
                const int br = wc * 64 + j * 16 + fr;
                fb[j] = *(const bf8_t*)&Bs[br * 64 + ((c * 4 + g) ^ (br & 7)) * 8];
            }
#pragma unroll
            for (int i = 0; i < NI; ++i)
#pragma unroll
                for (int j = 0; j < 4; ++j)
                    acc[i][j] = __builtin_amdgcn_mfma_f32_16x16x32_bf16(
                        fa[i], fb[j], acc[i][j], 0, 0, 0);
        }
        __syncthreads();
    }

    // ---- epilogue ----  D layout: col = lane&15 -> fr, row = g*4 + reg
#pragma unroll
    for (int j = 0; j < 4; ++j) {
        const int col = col0 + wc * 64 + j * 16 + fr;
        const float bcol = bias[col];
#pragma unroll
        for (int i = 0; i < NI; ++i) {
#pragma unroll
            for (int r = 0; r < 4; ++r) {
                const int row = row0 + wr * (BM / 2) + i * 16 + g * 4 + r;
                if (row >= R) continue;
                float vv = acc[i][j][r] + bcol;
                if (MODE == 2) {
                    out[(size_t)row * N + col] = fmaxf(vv, 0.f);
                } else if (MODE == 3) {
                    out[(size_t)row * N + col] = vv + res[(size_t)row * N + col];
                } else {
                    out[(size_t)row * N + col] = vv;
                }
            }
        }
    }
}

// ---------------------------------------------------------------------------
// Softmax over L*P=16 per head + bake sampling locations to pixel coords.
// oa row: [0..255] off (m*32+l*8+p*2+c), [256..383] attn logits (m*16+l*4+p).
// ---------------------------------------------------------------------------
__global__ __launch_bounds__(128) void softmax_loc_kernel(
    const float* __restrict__ oa, const float* __restrict__ ref,
    float* __restrict__ loc, float* __restrict__ attn)
{
    const int row = blockIdx.x;
    const int t   = threadIdx.x;       // 0..127 (m = t>>4)
    const float Wtab[L_] = {160.f, 80.f, 40.f, 20.f};
    const float Htab[L_] = {92.f, 46.f, 23.f, 12.f};

    float vlog = oa[(size_t)row * 384 + 256 + t];
    float mx = vlog;
#pragma unroll
    for (int o = 8; o >= 1; o >>= 1) mx = fmaxf(mx, __shfl_xor(mx, o, 64));
    const float e = __expf(vlog - mx);
    float sm = e;
#pragma unroll
    for (int o = 8; o >= 1; o >>= 1) sm += __shfl_xor(sm, o, 64);
    attn[(size_t)row * 128 + t] = e / sm;

    const int m = t >> 4, l = (t >> 2) & 3, p = t & 3;
    const float rx = ref[(size_t)row * 2 + 0];
    const float ry = ref[(size_t)row * 2 + 1];
    const int oi = m * 32 + l * 8 + p * 2;
    loc[(size_t)row * 256 + oi + 0] = rx * Wtab[l] + oa[(size_t)row * 384 + oi + 0] - 0.5f;
    loc[(size_t)row * 256 + oi + 1] = ry * Htab[l] + oa[(size_t)row * 384 + oi + 1] - 0.5f;
}

// ---------------------------------------------------------------------------
// Deformable sampling, bf16 v, vectorized: thread = (rl = t>>5, m = (t>>2)&7,
// dg = t&3); each thread computes 8 channels for all 16 points of its
// (row, m) via 16B ushort8 corner loads. 8 rows per block. Branch-free.
// ---------------------------------------------------------------------------
__global__ __launch_bounds__(256) void sample_kernel(
    const ushort_t* __restrict__ v, const float* __restrict__ loc,
    const float* __restrict__ attn, float* __restrict__ outf)
{
    const int row0 = blockIdx.x * 8;
    const int t    = threadIdx.x;
    const int rl   = t >> 5;          // 0..7
    const int m    = (t >> 2) & 7;    // 0..7
    const int dg   = t & 3;           // 0..3

    __shared__ float sloc[8][8][33];
    __shared__ float satt[8][8][17];

    {
        const float4* src = (const float4*)(loc + (size_t)row0 * 256);
#pragma unroll
        for (int i = 0; i < 2; ++i) {
            const int u   = i * 256 + t;        // 0..511
            const int r_  = u >> 6;
            const int rem = u & 63;
            const int m_  = rem >> 3;
            const int c4  = (rem & 7) * 4;
            *(float4*)&sloc[r_][m_][c4] = src[u];
        }
        const float4* asrc = (const float4*)(attn + (size_t)row0 * 128);
        {
            const int u   = t;
            const int r_  = u >> 5;
            const int rem = u & 31;
            const int m_  = rem >> 2;
            const int c4  = (rem & 3) * 4;
            *(float4*)&satt[r_][m_][c4] = asrc[u];
        }
    }
    __syncthreads();

    const int row = row0 + rl;
    const int b   = row / NQ_;
    const ushort_t* vbase = v + (((size_t)(b * M_ + m)) * S_) * D_ + dg * 8;

    const int Wtab[L_] = {160, 80, 40, 20};
    const int Htab[L_] = {92, 46, 23, 12};
    const int Stab[L_] = {0, 14720, 18400, 19320};

    float acc[8] = {};

#pragma unroll
    for (int l = 0; l < L_; ++l) {
        const int Wl = Wtab[l], Hl = Htab[l], st = Stab[l];
#pragma unroll
        for (int p = 0; p < P_; ++p) {
            const float x = sloc[rl][m][l * 8 + p * 2 + 0];
            const float y = sloc[rl][m][l * 8 + p * 2 + 1];
            const float a = satt[rl][m][l * 4 + p];
            const float xf = floorf(x), yf = floorf(y);
            const int x0 = (int)xf, y0 = (int)yf;
            const float lx = x - xf, ly = y - yf;
            const float wx0 = (x0 >= 0 && x0 < Wl)         ? (1.f - lx) : 0.f;
            const float wx1 = (x0 + 1 >= 0 && x0 + 1 < Wl) ? lx         : 0.f;
            const float wy0 = (y0 >= 0 && y0 < Hl)         ? (1.f - ly) : 0.f;
            const float wy1 = (y0 + 1 >= 0 && y0 + 1 < Hl) ? ly         : 0.f;
            const float ay0 = a * wy0, ay1 = a * wy1;
            const float aw00 = ay0 * wx0, aw01 = ay0 * wx1;
            const float aw10 = ay1 * wx0, aw11 = ay1 * wx1;
            const int xc0 = min(max(x0, 0), Wl - 1);
            const int xc1 = min(max(x0 + 1, 0), Wl - 1);
            const int yc0 = min(max(y0, 0), Hl - 1);
            const int yc1 = min(max(y0 + 1, 0), Hl - 1);
            const us8_t s00 = *(const us8_t*)(vbase + (size_t)(st + yc0 * Wl + xc0) * D_);
            const us8_t s01 = *(const us8_t*)(vbase + (size_t)(st + yc0 * Wl + xc1) * D_);
            const us8_t s10 = *(const us8_t*)(vbase + (size_t)(st + yc1 * Wl + xc0) * D_);
            const us8_t s11 = *(const us8_t*)(vbase + (size_t)(st + yc1 * Wl + xc1) * D_);
#pragma unroll
            for (int j = 0; j < 8; ++j)
                acc[j] += aw00 * bfu2f(s00[j]) + aw01 * bfu2f(s01[j])
                        + aw10 * bfu2f(s10[j]) + aw11 * bfu2f(s11[j]);
        }
    }

    float* o = outf + (size_t)row * 256 + m * 32 + dg * 8;
    *(float4*)o       = make_float4(acc[0], acc[1], acc[2], acc[3]);
    *((float4*)o + 1) = make_float4(acc[4], acc[5], acc[6], acc[7]);
}

// ---------------------------------------------------------------------------
// LayerNorm over C=256. grid = 7200, block = 64 (one wave), float4 per lane.
// ---------------------------------------------------------------------------
__global__ __launch_bounds__(64) void ln_kernel(
    const float* __restrict__ in, const float* __restrict__ w,
    const float* __restrict__ bp, float* __restrict__ out)
{
    const int row  = blockIdx.x;
    const int lane = threadIdx.x;
    const float4 x = ((const float4*)(in + (size_t)row * C_))[lane];
    float s = x.x + x.y + x.z + x.w;
#pragma unroll
    for (int o = 32; o >= 1; o >>= 1) s += __shfl_xor(s, o, 64);
    const float mean = s * (1.f / C_);
    const float d0 = x.x - mean, d1 = x.y - mean, d2 = x.z - mean, d3 = x.w - mean;
    float ss = d0 * d0 + d1 * d1 + d2 * d2 + d3 * d3;
#pragma unroll
    for (int o = 32; o >= 1; o >>= 1) ss += __shfl_xor(ss, o, 64);
    const float r = rsqrtf(ss * (1.f / C_) + 1e-6f);
    const float4 wv = ((const float4*)w)[lane];
    const float4 bv = ((const float4*)bp)[lane];
    float4 o4;
    o4.x = d0 * r * wv.x + bv.x;
    o4.y = d1 * r * wv.y + bv.y;
    o4.z = d2 * r * wv.z + bv.z;
    o4.w = d3 * r * wv.w + bv.w;
    ((float4*)(out + (size_t)row * C_))[lane] = o4;
}

// ---------------------------------------------------------------------------
// Classifier head: out[row,0..9] = x[row,:] @ w_cls + b_cls. grid=7200, block=64.
// ---------------------------------------------------------------------------
__global__ __launch_bounds__(64) void cls_kernel(
    const float* __restrict__ x, const float* __restrict__ w,
    const float* __restrict__ bias, float* __restrict__ out)
{
    const int row  = blockIdx.x;
    const int lane = threadIdx.x;
    float acc[NC_] = {};
#pragma unroll
    for (int j = 0; j < 4; ++j) {
        const int k = lane + j * 64;
        const float xk = x[(size_t)row * C_ + k];
        const float* wr = w + (size_t)k * NC_;
#pragma unroll
        for (int n = 0; n < NC_; ++n) acc[n] += xk * wr[n];
    }
#pragma unroll
    for (int n = 0; n < NC_; ++n) {
        float s = acc[n];
#pragma unroll
        for (int o = 32; o >= 1; o >>= 1) s += __shfl_xor(s, o, 64);
        if (lane == n) out[(size_t)row * NC_ + n] = s + bias[n];
    }
}

// ---------------------------------------------------------------------------
extern "C" void kernel_launch(void* const* d_in, const int* in_sizes, int n_in,
                              void* d_out, int out_size, void* d_ws, size_t ws_size,
                              hipStream_t stream)
{
    const float* query   = (const float*)d_in[0];
    const float* value   = (const float*)d_in[1];
    const float* refp    = (const float*)d_in[2];
    const float* w_value = (const float*)d_in[3];
    const float* b_value = (const float*)d_in[4];
    const float* w_off   = (const float*)d_in[5];
    const float* b_off   = (const float*)d_in[6];
    const float* w_attn  = (const float*)d_in[7];
    const float* b_attn  = (const float*)d_in[8];
    const float* w_out   = (const float*)d_in[9];
    const float* b_out   = (const float*)d_in[10];
    const float* ln1w    = (const float*)d_in[11];
    const float* ln1b    = (const float*)d_in[12];
    const float* w_ffn1  = (const float*)d_in[13];
    const float* b_ffn1  = (const float*)d_in[14];
    const float* w_ffn2  = (const float*)d_in[15];
    const float* b_ffn2  = (const float*)d_in[16];
    const float* ln2w    = (const float*)d_in[17];
    const float* ln2b    = (const float*)d_in[18];
    const float* w_cls   = (const float*)d_in[19];
    const float* b_cls   = (const float*)d_in[20];

    // ---- workspace layout ----
    short* WvT   = (short*)d_ws;            //  65536
    short* WoaT  = WvT  + 65536;            //  98304 (384x256)
    short* WoutT = WoaT + 98304;            //  65536
    short* Wf1T  = WoutT + 65536;           // 262144 (1024x256)
    short* Wf2T  = Wf1T + 262144;           // 262144 (256x1024)
    float* bias_cat = (float*)(Wf2T + 262144);            // 384
    ushort_t* v = (ushort_t*)(bias_cat + 384);            // [B,M,S,D] bf16, 80 MB
    float* oa   = (float*)(v + (size_t)RV_ * C_);         // [RQ,384]
    float* loc  = oa   + (size_t)RQ_ * 384;               // [RQ,256]
    float* attn = loc  + (size_t)RQ_ * 256;               // [RQ,128]
    float* feat = attn + (size_t)RQ_ * 128;               // [RQ,256]
    float* tmp  = feat + (size_t)RQ_ * 256;               // [RQ,256]
    float* h    = tmp  + (size_t)RQ_ * 256;               // [RQ,1024]
    float* x2   = h    + (size_t)RQ_ * FFN_;              // [RQ,256]

    // 0) weight prep (bf16 + transpose), bias concat
    prep_weights<<<dim3(64, 1, 5), 256, 0, stream>>>(
        w_value, w_off, w_attn, w_out, w_ffn1, w_ffn2,
        WvT, WoaT, WoutT, Wf1T, Wf2T);
    prep_bias<<<1, 384, 0, stream>>>(b_off, b_attn, bias_cat);

    // 1) v = value @ w_value + b_value  -> bf16 [B,M,S,D]  (BN=256, A read once)
    gemm_value<<<(RV_ + 127) / 128, 512, 0, stream>>>(
        value, WvT, b_value, v, RV_);

    // 2) fused off|attn logits
    gemm_mfma<0, 64><<<dim3((RQ_ + 63) / 64, 3), 256, 0, stream>>>(
        query, WoaT, bias_cat, nullptr, oa, RQ_, 384, 256);

    // 3) softmax + pixel-coord locations
    softmax_loc_kernel<<<RQ_, 128, 0, stream>>>(oa, refp, loc, attn);

    // 4) deformable sampling -> feat [RQ, C]
    sample_kernel<<<RQ_ / 8, 256, 0, stream>>>(v, loc, attn, feat);

    // 5) tmp = query + feat @ w_out + b_out
    gemm_mfma<3, 64><<<dim3((RQ_ + 63) / 64, 2), 256, 0, stream>>>(
        feat, WoutT, b_out, query, tmp, RQ_, 256, 256);

    // 6) x1 = LN(tmp) -> feat reused
    ln_kernel<<<RQ_, 64, 0, stream>>>(tmp, ln1w, ln1b, feat);

    // 7) h = relu(x1 @ w_ffn1 + b_ffn1)
    gemm_mfma<2, 64><<<dim3((RQ_ + 63) / 64, 8), 256, 0, stream>>>(
        feat, Wf1T, b_ffn1, nullptr, h, RQ_, 1024, 256);

    // 8) tmp = x1 + h @ w_ffn2 + b_ffn2
    gemm_mfma<3, 64><<<dim3((RQ_ + 63) / 64, 2), 256, 0, stream>>>(
        h, Wf2T, b_ffn2, feat, tmp, RQ_, 256, 1024);

    // 9) x2 = LN(tmp)
    ln_kernel<<<RQ_, 64, 0, stream>>>(tmp, ln2w, ln2b, x2);

    // 10) out = x2 @ w_cls + b_cls
    cls_kernel<<<RQ_, 64, 0, stream>>>(x2, w_cls, b_cls, (float*)d_out);
}